// Round 2
// baseline (721.252 us; speedup 1.0000x reference)
//
#include <hip/hip_runtime.h>

#define VQ_D 64
#define VQ_K 1024
#define VQ_BLOCK 256

__global__ __launch_bounds__(VQ_BLOCK) void vq_argmin_kernel(
    const float* __restrict__ x,
    const float* __restrict__ w,
    float* __restrict__ qout,
    float* __restrict__ iout) {
    __shared__ float wsq[VQ_K];

    const int t = threadIdx.x;

    // Per-block compute of ||w_k||^2 into LDS (1024x64 FMAs across 256 threads).
    for (int k = t; k < VQ_K; k += VQ_BLOCK) {
        const float4* wr = reinterpret_cast<const float4*>(w + (size_t)k * VQ_D);
        float sx = 0.f, sy = 0.f, sz = 0.f, sw = 0.f;
#pragma unroll
        for (int j = 0; j < VQ_D / 4; ++j) {
            float4 v = wr[j];
            sx = fmaf(v.x, v.x, sx);
            sy = fmaf(v.y, v.y, sy);
            sz = fmaf(v.z, v.z, sz);
            sw = fmaf(v.w, v.w, sw);
        }
        wsq[k] = (sx + sy) + (sz + sw);
    }
    __syncthreads();

    const long long row = (long long)blockIdx.x * VQ_BLOCK + t;

    // Load this thread's x row into registers (64 floats = 16 float4).
    const float4* xp = reinterpret_cast<const float4*>(x + row * VQ_D);
    float4 xr[16];
#pragma unroll
    for (int j = 0; j < 16; ++j) xr[j] = xp[j];

    float xsq;
    {
        float sx = 0.f, sy = 0.f, sz = 0.f, sw = 0.f;
#pragma unroll
        for (int j = 0; j < 16; ++j) {
            sx = fmaf(xr[j].x, xr[j].x, sx);
            sy = fmaf(xr[j].y, xr[j].y, sy);
            sz = fmaf(xr[j].z, xr[j].z, sz);
            sw = fmaf(xr[j].w, xr[j].w, sw);
        }
        xsq = (sx + sy) + (sz + sw);
    }

    float best = 3.402823466e38f;
    int bidx = 0;

    // Hot loop: k is wave-uniform -> weight reads should scalarize to s_load,
    // leaving a pure v_fma stream on the x registers.
    for (int k = 0; k < VQ_K; ++k) {
        const float4* wr = reinterpret_cast<const float4*>(w + (size_t)k * VQ_D);
        float ax = 0.f, ay = 0.f, az = 0.f, aw = 0.f;
#pragma unroll
        for (int j = 0; j < 16; ++j) {
            float4 v = wr[j];
            ax = fmaf(xr[j].x, v.x, ax);
            ay = fmaf(xr[j].y, v.y, ay);
            az = fmaf(xr[j].z, v.z, az);
            aw = fmaf(xr[j].w, v.w, aw);
        }
        float dot = (ax + ay) + (az + aw);
        // Mirror reference elementwise order: (x_sq - 2*dot) + w_sq
        float s = (xsq - 2.0f * dot) + wsq[k];
        if (s < best) {  // strict < == first-occurrence argmin (jnp semantics)
            best = s;
            bidx = k;
        }
    }

    // Epilogue: gather winning codeword, emit fp32.
    const float4* br = reinterpret_cast<const float4*>(w + (size_t)bidx * VQ_D);
    float4* qo = reinterpret_cast<float4*>(qout + row * VQ_D);
#pragma unroll
    for (int j = 0; j < 16; ++j) {
        qo[j] = br[j];
    }
    iout[row] = (float)bidx;
}

extern "C" void kernel_launch(void* const* d_in, const int* in_sizes, int n_in,
                              void* d_out, int out_size, void* d_ws, size_t ws_size,
                              hipStream_t stream) {
    const float* x = (const float*)d_in[0];
    const float* w = (const float*)d_in[1];
    const int N = in_sizes[0] / VQ_D;  // 262144

    float* qout = (float*)d_out;
    float* iout = qout + (size_t)N * VQ_D;

    vq_argmin_kernel<<<N / VQ_BLOCK, VQ_BLOCK, 0, stream>>>(x, w, qout, iout);
}

// Round 3
// 446.903 us; speedup vs baseline: 1.6139x; 1.6139x over previous
//
#include <hip/hip_runtime.h>
#include <hip/hip_bf16.h>

#define VQ_D   64
#define VQ_K   1024
#define ROWS_PER_BLOCK 128
#define KTILE  128          // codes per K-tile
#define NKT    (VQ_K / KTILE)
#define LSTRIDE 72          // shorts per LDS row (144 B = 9*16B, bank-friendly)
#define EPS    0.05f

typedef __attribute__((ext_vector_type(8))) short short8_t;
typedef __attribute__((ext_vector_type(4))) float f32x4;

static __device__ __forceinline__ short f2bf_s(float f) {
    __hip_bfloat16 b = __float2bfloat16(f);
    short s; __builtin_memcpy(&s, &b, 2); return s;
}
static __device__ __forceinline__ float bf2f(short s) {
    __hip_bfloat16 b; __builtin_memcpy(&b, &s, 2); return __bfloat162float(b);
}

// ---------------- kernel 0: split w into hi/lo bf16, compute wsq, zero counter
__global__ __launch_bounds__(256) void vq_prep_kernel(
    const float* __restrict__ w,
    short* __restrict__ whg, short* __restrict__ wlg,
    float* __restrict__ wsq_g, int* __restrict__ counter) {
    const int c = blockIdx.x * 256 + threadIdx.x;   // code id, grid = K/256
    if (blockIdx.x == 0 && threadIdx.x == 0) *counter = 0;
    if (c >= VQ_K) return;
    const f32x4* wr = reinterpret_cast<const f32x4*>(w + (size_t)c * VQ_D);
    float sx = 0.f, sy = 0.f, sz = 0.f, sw = 0.f;
#pragma unroll
    for (int j = 0; j < 16; ++j) {
        f32x4 v = wr[j];
        // hi/lo split (exact residual in fp32)
        short hx = f2bf_s(v[0]), hy = f2bf_s(v[1]), hz = f2bf_s(v[2]), hw = f2bf_s(v[3]);
        short lx = f2bf_s(v[0] - bf2f(hx)), ly = f2bf_s(v[1] - bf2f(hy));
        short lz = f2bf_s(v[2] - bf2f(hz)), lw = f2bf_s(v[3] - bf2f(hw));
        short4 hi4; hi4.x = hx; hi4.y = hy; hi4.z = hz; hi4.w = hw;
        short4 lo4; lo4.x = lx; lo4.y = ly; lo4.z = lz; lo4.w = lw;
        *reinterpret_cast<short4*>(whg + (size_t)c * VQ_D + j * 4) = hi4;
        *reinterpret_cast<short4*>(wlg + (size_t)c * VQ_D + j * 4) = lo4;
        // wsq: EXACT same formula as the round-2 kernel that matched ref bit-for-bit
        sx = fmaf(v[0], v[0], sx); sy = fmaf(v[1], v[1], sy);
        sz = fmaf(v[2], v[2], sz); sw = fmaf(v[3], v[3], sw);
    }
    wsq_g[c] = (sx + sy) + (sz + sw);
}

// ---------------- kernel 1: MFMA split-bf16 scores + per-row top-2 + outputs
__global__ __launch_bounds__(256) void vq_main_kernel(
    const float* __restrict__ x,
    const short* __restrict__ whg, const short* __restrict__ wlg,
    const float* __restrict__ wsq_g,
    const float* __restrict__ w,        // fp32 for gather
    float* __restrict__ qout, float* __restrict__ iout,
    int* __restrict__ counter, int* __restrict__ list, int cap) {

    __shared__ __align__(16) short xh[ROWS_PER_BLOCK * LSTRIDE];
    __shared__ __align__(16) short xl[ROWS_PER_BLOCK * LSTRIDE];
    __shared__ __align__(16) short whl[KTILE * LSTRIDE];
    __shared__ __align__(16) short wll[KTILE * LSTRIDE];
    __shared__ float wsqLds[VQ_K];
    __shared__ int   idxRow[ROWS_PER_BLOCK];
    __shared__ float gapRow[ROWS_PER_BLOCK];

    const int t    = threadIdx.x;
    const int wid  = t >> 6;
    const int lane = t & 63;
    const int quad = lane >> 4;
    const int ln15 = lane & 15;
    const long long rowBase = (long long)blockIdx.x * ROWS_PER_BLOCK;

    // ---- stage x rows -> hi/lo bf16 in LDS (144B stride)
#pragma unroll
    for (int pass = 0; pass < 8; ++pass) {
        int row = pass * 16 + (t >> 4);
        int seg = t & 15;                       // float4 segment 0..15
        f32x4 v = reinterpret_cast<const f32x4*>(x + (rowBase + row) * VQ_D)[seg];
        short4 hi4, lo4;
        short hx = f2bf_s(v[0]), hy = f2bf_s(v[1]), hz = f2bf_s(v[2]), hw = f2bf_s(v[3]);
        hi4.x = hx; hi4.y = hy; hi4.z = hz; hi4.w = hw;
        lo4.x = f2bf_s(v[0] - bf2f(hx)); lo4.y = f2bf_s(v[1] - bf2f(hy));
        lo4.z = f2bf_s(v[2] - bf2f(hz)); lo4.w = f2bf_s(v[3] - bf2f(hw));
        *reinterpret_cast<short4*>(xh + row * LSTRIDE + seg * 4) = hi4;
        *reinterpret_cast<short4*>(xl + row * LSTRIDE + seg * 4) = lo4;
    }
    // ---- stage wsq
#pragma unroll
    for (int i = 0; i < VQ_K / 256; ++i) wsqLds[i * 256 + t] = wsq_g[i * 256 + t];
    __syncthreads();

    // ---- load A fragments (held in VGPRs for the whole kernel)
    short8_t ah[2][2], al[2][2];
#pragma unroll
    for (int rt = 0; rt < 2; ++rt)
#pragma unroll
        for (int ks = 0; ks < 2; ++ks) {
            const short* p = xh + (wid * 32 + rt * 16 + ln15) * LSTRIDE + ks * 32 + quad * 8;
            ah[rt][ks] = *reinterpret_cast<const short8_t*>(p);
            const short* q = xl + (wid * 32 + rt * 16 + ln15) * LSTRIDE + ks * 32 + quad * 8;
            al[rt][ks] = *reinterpret_cast<const short8_t*>(q);
        }

    float m1[2][4], m2[2][4]; int i1[2][4];
#pragma unroll
    for (int rt = 0; rt < 2; ++rt)
#pragma unroll
        for (int r = 0; r < 4; ++r) { m1[rt][r] = 3.402823466e38f; m2[rt][r] = 3.402823466e38f; i1[rt][r] = 0; }

    for (int kt = 0; kt < NKT; ++kt) {
        __syncthreads();   // previous tile reads complete before overwrite
        // stage w hi/lo K-tile (16B chunks; 128 codes x 8 segs x 2 arrays / 256 thr = 8 iters)
#pragma unroll
        for (int i = 0; i < 4; ++i) {
            int idx = i * 256 + t;             // 0..1023
            int code = idx >> 3, seg = idx & 7;
            *reinterpret_cast<f32x4*>(whl + code * LSTRIDE + seg * 8) =
                *reinterpret_cast<const f32x4*>(whg + ((size_t)(kt * KTILE + code)) * VQ_D + seg * 8);
            *reinterpret_cast<f32x4*>(wll + code * LSTRIDE + seg * 8) =
                *reinterpret_cast<const f32x4*>(wlg + ((size_t)(kt * KTILE + code)) * VQ_D + seg * 8);
        }
        __syncthreads();

#pragma unroll
        for (int ct = 0; ct < KTILE / 16; ++ct) {
            const short* bp = whl + (ct * 16 + ln15) * LSTRIDE + quad * 8;
            const short* lp = wll + (ct * 16 + ln15) * LSTRIDE + quad * 8;
            short8_t bh0 = *reinterpret_cast<const short8_t*>(bp);
            short8_t bh1 = *reinterpret_cast<const short8_t*>(bp + 32);
            short8_t bl0 = *reinterpret_cast<const short8_t*>(lp);
            short8_t bl1 = *reinterpret_cast<const short8_t*>(lp + 32);
            const int   kc   = kt * KTILE + ct * 16 + ln15;   // this lane's code id
            const float wsqc = wsqLds[kc];

#pragma unroll
            for (int rt = 0; rt < 2; ++rt) {
                f32x4 acc = {0.f, 0.f, 0.f, 0.f};
                acc = __builtin_amdgcn_mfma_f32_16x16x32_bf16(ah[rt][0], bh0, acc, 0, 0, 0);
                acc = __builtin_amdgcn_mfma_f32_16x16x32_bf16(al[rt][0], bh0, acc, 0, 0, 0);
                acc = __builtin_amdgcn_mfma_f32_16x16x32_bf16(ah[rt][0], bl0, acc, 0, 0, 0);
                acc = __builtin_amdgcn_mfma_f32_16x16x32_bf16(ah[rt][1], bh1, acc, 0, 0, 0);
                acc = __builtin_amdgcn_mfma_f32_16x16x32_bf16(al[rt][1], bh1, acc, 0, 0, 0);
                acc = __builtin_amdgcn_mfma_f32_16x16x32_bf16(ah[rt][1], bl1, acc, 0, 0, 0);
#pragma unroll
                for (int r = 0; r < 4; ++r) {
                    float s = fmaf(-2.0f, acc[r], wsqc);      // xsq dropped: row-constant
                    bool lt = s < m1[rt][r];
                    m2[rt][r] = fminf(m2[rt][r], fmaxf(s, m1[rt][r]));
                    i1[rt][r] = lt ? kc : i1[rt][r];
                    m1[rt][r] = fminf(m1[rt][r], s);
                }
            }
        }
    }

    // ---- cross-lane top-2 merge within each quad-group of 16 lanes
#pragma unroll
    for (int rt = 0; rt < 2; ++rt)
#pragma unroll
        for (int r = 0; r < 4; ++r) {
            float a1 = m1[rt][r]; int ai = i1[rt][r]; float a2 = m2[rt][r];
#pragma unroll
            for (int mask = 1; mask < 16; mask <<= 1) {
                float b1 = __shfl_xor(a1, mask, 64);
                int   bi = __shfl_xor(ai, mask, 64);
                float b2 = __shfl_xor(a2, mask, 64);
                float n2 = fminf(fminf(a2, b2), fmaxf(a1, b1));
                if (b1 < a1 || (b1 == a1 && bi < ai)) { a1 = b1; ai = bi; }
                a2 = n2;
            }
            if (ln15 == 0) {
                int row = wid * 32 + rt * 16 + quad * 4 + r;
                idxRow[row] = ai;
                gapRow[row] = a2 - a1;
            }
        }
    __syncthreads();

    // ---- outputs: indices, ambiguity flags, gathered codewords
    if (t < ROWS_PER_BLOCK) {
        iout[rowBase + t] = (float)idxRow[t];
        if (gapRow[t] < EPS) {
            int pos = atomicAdd(counter, 1);
            if (pos < cap) list[pos] = (int)(rowBase + t);
        }
    }
#pragma unroll
    for (int it = 0; it < 8; ++it) {
        int cid = it * 256 + t;            // 2048 float4 chunks
        int row = cid >> 4, seg = cid & 15;
        int idx = idxRow[row];
        reinterpret_cast<f32x4*>(qout + (rowBase + row) * VQ_D)[seg] =
            reinterpret_cast<const f32x4*>(w + (size_t)idx * VQ_D)[seg];
    }
}

// ---------------- kernel 2: exact fp32 re-solve of flagged rows (wave per row)
__global__ __launch_bounds__(256) void vq_fix_kernel(
    const float* __restrict__ x, const float* __restrict__ w,
    const float* __restrict__ wsq_g,
    const int* __restrict__ counter, const int* __restrict__ list, int cap,
    float* __restrict__ qout, float* __restrict__ iout, int N) {

    const int lane = threadIdx.x & 63;
    const int waveId = (blockIdx.x * 256 + threadIdx.x) >> 6;
    const int nWaves = (gridDim.x * 256) >> 6;
    int cnt = *counter;
    bool overflow = cnt > cap;
    int nwork = overflow ? N : cnt;

    for (int i = waveId; i < nwork; i += nWaves) {
        int row = overflow ? i : list[i];
        const f32x4* xr = reinterpret_cast<const f32x4*>(x + (size_t)row * VQ_D);
        f32x4 xv[16];
#pragma unroll
        for (int j = 0; j < 16; ++j) xv[j] = xr[j];
        float sx = 0.f, sy = 0.f, sz = 0.f, sw = 0.f;
#pragma unroll
        for (int j = 0; j < 16; ++j) {
            sx = fmaf(xv[j][0], xv[j][0], sx); sy = fmaf(xv[j][1], xv[j][1], sy);
            sz = fmaf(xv[j][2], xv[j][2], sz); sw = fmaf(xv[j][3], xv[j][3], sw);
        }
        float xsq = (sx + sy) + (sz + sw);

        float bm = 3.402823466e38f; int bk = 0x7fffffff;
        for (int kk = 0; kk < VQ_K / 64; ++kk) {
            int k = kk * 64 + lane;
            const f32x4* wr = reinterpret_cast<const f32x4*>(w + (size_t)k * VQ_D);
            float ax = 0.f, ay = 0.f, az = 0.f, aw = 0.f;
#pragma unroll
            for (int j = 0; j < 16; ++j) {
                f32x4 v = wr[j];
                ax = fmaf(xv[j][0], v[0], ax); ay = fmaf(xv[j][1], v[1], ay);
                az = fmaf(xv[j][2], v[2], az); aw = fmaf(xv[j][3], v[3], aw);
            }
            float dot = (ax + ay) + (az + aw);
            float s = (xsq - 2.0f * dot) + wsq_g[k];   // identical to round-2 formula
            if (s < bm) { bm = s; bk = k; }            // per-lane ks ascend: first-occurrence
        }
#pragma unroll
        for (int mask = 1; mask < 64; mask <<= 1) {
            float om = __shfl_xor(bm, mask, 64);
            int   ok = __shfl_xor(bk, mask, 64);
            if (om < bm || (om == bm && ok < bk)) { bm = om; bk = ok; }
        }
        if (lane == 0) iout[row] = (float)bk;
        qout[(size_t)row * VQ_D + lane] = w[(size_t)bk * VQ_D + lane];
    }
}

extern "C" void kernel_launch(void* const* d_in, const int* in_sizes, int n_in,
                              void* d_out, int out_size, void* d_ws, size_t ws_size,
                              hipStream_t stream) {
    const float* x = (const float*)d_in[0];
    const float* w = (const float*)d_in[1];
    const int N = in_sizes[0] / VQ_D;      // 262144

    float* qout = (float*)d_out;
    float* iout = qout + (size_t)N * VQ_D;

    // workspace layout
    char* ws = (char*)d_ws;
    short* whg   = (short*)(ws);                       // 1024*64*2 = 131072 B
    short* wlg   = (short*)(ws + 131072);              // 131072 B
    float* wsq_g = (float*)(ws + 262144);              // 4096 B
    int*   counter = (int*)(ws + 266240);              // 4 B
    int*   list    = (int*)(ws + 266244);
    long long capLL = ((long long)ws_size - 266244) / 4;
    int cap = capLL < 0 ? 0 : (capLL > N ? N : (int)capLL);

    vq_prep_kernel<<<VQ_K / 256, 256, 0, stream>>>(w, whg, wlg, wsq_g, counter);
    vq_main_kernel<<<N / ROWS_PER_BLOCK, 256, 0, stream>>>(
        x, whg, wlg, wsq_g, w, qout, iout, counter, list, cap);
    vq_fix_kernel<<<256, 256, 0, stream>>>(x, w, wsq_g, counter, list, cap, qout, iout, N);
}

// Round 4
// 329.986 us; speedup vs baseline: 2.1857x; 1.3543x over previous
//
#include <hip/hip_runtime.h>
#include <hip/hip_bf16.h>

#define VQ_D   64
#define VQ_K   1024
#define KTILE  64                    // codes per staged tile
#define NKT    (VQ_K / KTILE)        // 16
#define ROWS_PER_BLOCK 256           // 4 waves x 64 rows
#define EPS    0.015f

typedef __attribute__((ext_vector_type(8))) short short8_t;
typedef __attribute__((ext_vector_type(4))) float f32x4;

static __device__ __forceinline__ short f2bf_s(float f) {
    __hip_bfloat16 b = __float2bfloat16(f);
    short s; __builtin_memcpy(&s, &b, 2); return s;
}
static __device__ __forceinline__ float bf2f(short s) {
    __hip_bfloat16 b; __builtin_memcpy(&b, &s, 2); return __bfloat162float(b);
}

// async 16B/lane global->LDS; lds dst must be wave-uniform (lands at lds + lane*16)
#define ASYNC_CP16(gp, lp)                                                        \
    __builtin_amdgcn_global_load_lds(                                             \
        (const __attribute__((address_space(1))) unsigned int*)(gp),              \
        (__attribute__((address_space(3))) unsigned int*)(lp), 16, 0, 0)

// ---------------- kernel 0: swizzle w into MFMA-fragment order (hi/lo bf16) + wsq
// wS layout: tile T (64 codes) = 8192 shorts; chunk c16 = a*8 + g*2 + b (a=hi/lo,
// g=16-code group, b=kblock) = 512 shorts; slot s = q*16 + l = 8 shorts
//   chunk[c16][s] = split_a( w[T*64 + g*16 + l][b*32 + q*8 .. +7] )
__global__ __launch_bounds__(256) void vq_prep_kernel(
    const float* __restrict__ w, short* __restrict__ wS,
    float* __restrict__ wsq_g, int* __restrict__ counter) {
    const int c = blockIdx.x * 256 + threadIdx.x;
    if (c == 0) *counter = 0;
    if (c >= VQ_K) return;
    const int T = c >> 6, g = (c >> 4) & 3, l = c & 15;
    short* tbase = wS + (size_t)T * 8192;
    float sx = 0.f, sy = 0.f, sz = 0.f, sw = 0.f;
#pragma unroll
    for (int b = 0; b < 2; ++b)
#pragma unroll
        for (int q = 0; q < 4; ++q) {
            const float* src = w + (size_t)c * VQ_D + b * 32 + q * 8;
            f32x4 v0 = *reinterpret_cast<const f32x4*>(src);
            f32x4 v1 = *reinterpret_cast<const f32x4*>(src + 4);
            float vv[8] = {v0[0], v0[1], v0[2], v0[3], v1[0], v1[1], v1[2], v1[3]};
            short8_t hs, ls;
#pragma unroll
            for (int j = 0; j < 8; ++j) {
                short h = f2bf_s(vv[j]);
                hs[j] = h;
                ls[j] = f2bf_s(vv[j] - bf2f(h));
            }
            *reinterpret_cast<short8_t*>(tbase + (g * 2 + b) * 512 + (q * 16 + l) * 8) = hs;
            *reinterpret_cast<short8_t*>(tbase + 4096 + (g * 2 + b) * 512 + (q * 16 + l) * 8) = ls;
            // wsq in EXACT round-2 partial order (j ascending, 4 lane-partials)
            sx = fmaf(v0[0], v0[0], sx); sy = fmaf(v0[1], v0[1], sy);
            sz = fmaf(v0[2], v0[2], sz); sw = fmaf(v0[3], v0[3], sw);
            sx = fmaf(v1[0], v1[0], sx); sy = fmaf(v1[1], v1[1], sy);
            sz = fmaf(v1[2], v1[2], sz); sw = fmaf(v1[3], v1[3], sw);
        }
    wsq_g[c] = (sx + sy) + (sz + sw);
}

// ---------------- kernel 1: MFMA split-bf16 scores, top-2, outputs
__global__ __launch_bounds__(256, 3) void vq_main_kernel(
    const float* __restrict__ x, const short* __restrict__ wS,
    const float* __restrict__ wsq_g, const float* __restrict__ w,
    float* __restrict__ qout, float* __restrict__ iout,
    int* __restrict__ counter, int* __restrict__ list, int cap) {

    __shared__ __align__(16) short wbuf[2][8192];   // double-buffered w tiles, 32 KB
    __shared__ float wsqLds[VQ_K];
    __shared__ int   idxRow[ROWS_PER_BLOCK];
    __shared__ float gapRow[ROWS_PER_BLOCK];

    const int t    = threadIdx.x;
    const int wid  = t >> 6;
    const int lane = t & 63;
    const int quad = lane >> 4;
    const int ln15 = lane & 15;
    const long long rowBase = (long long)blockIdx.x * ROWS_PER_BLOCK;

    // ---- kick off tile 0 staging immediately (overlaps A-frag conversion)
#pragma unroll
    for (int i = 0; i < 4; ++i) {
        const int c16 = wid * 4 + i;
        const short* gp = wS + c16 * 512 + lane * 8;
        ASYNC_CP16(gp, &wbuf[0][c16 * 512]);
    }

    // ---- A fragments straight from global x (per-lane 8 consecutive floats)
    short8_t ah[4][2], al[4][2];
#pragma unroll
    for (int rt = 0; rt < 4; ++rt)
#pragma unroll
        for (int ks = 0; ks < 2; ++ks) {
            const float* xp = x + (rowBase + wid * 64 + rt * 16 + ln15) * VQ_D + ks * 32 + quad * 8;
            f32x4 v0 = *reinterpret_cast<const f32x4*>(xp);
            f32x4 v1 = *reinterpret_cast<const f32x4*>(xp + 4);
            float vv[8] = {v0[0], v0[1], v0[2], v0[3], v1[0], v1[1], v1[2], v1[3]};
#pragma unroll
            for (int j = 0; j < 8; ++j) {
                short h = f2bf_s(vv[j]);
                ah[rt][ks][j] = h;
                al[rt][ks][j] = f2bf_s(vv[j] - bf2f(h));
            }
        }

    // ---- wsq -> LDS
#pragma unroll
    for (int i = 0; i < 4; ++i) wsqLds[i * 256 + t] = wsq_g[i * 256 + t];

    float m1[4][4], m2[4][4]; int i1[4][4];
#pragma unroll
    for (int rt = 0; rt < 4; ++rt)
#pragma unroll
        for (int r = 0; r < 4; ++r) {
            m1[rt][r] = 3.402823466e38f; m2[rt][r] = 3.402823466e38f; i1[rt][r] = 0;
        }

    __syncthreads();   // tile 0 + wsq ready

    const int fragoff = (quad * 16 + ln15) * 8;
    for (int kt = 0; kt < NKT; ++kt) {
        const int cur = kt & 1;
        if (kt + 1 < NKT) {
#pragma unroll
            for (int i = 0; i < 4; ++i) {
                const int c16 = wid * 4 + i;
                const short* gp = wS + (size_t)(kt + 1) * 8192 + c16 * 512 + lane * 8;
                ASYNC_CP16(gp, &wbuf[1 - cur][c16 * 512]);
            }
        }
        const short* bufp = wbuf[cur];
#pragma unroll
        for (int ct = 0; ct < 4; ++ct) {
            short8_t bh0 = *reinterpret_cast<const short8_t*>(bufp + (ct * 2 + 0) * 512 + fragoff);
            short8_t bh1 = *reinterpret_cast<const short8_t*>(bufp + (ct * 2 + 1) * 512 + fragoff);
            short8_t bl0 = *reinterpret_cast<const short8_t*>(bufp + 4096 + (ct * 2 + 0) * 512 + fragoff);
            short8_t bl1 = *reinterpret_cast<const short8_t*>(bufp + 4096 + (ct * 2 + 1) * 512 + fragoff);
            const int   kc   = kt * KTILE + ct * 16 + ln15;
            const float wsqc = wsqLds[kc];
#pragma unroll
            for (int rt = 0; rt < 4; ++rt) {
                f32x4 acc = {0.f, 0.f, 0.f, 0.f};
                acc = __builtin_amdgcn_mfma_f32_16x16x32_bf16(ah[rt][0], bh0, acc, 0, 0, 0);
                acc = __builtin_amdgcn_mfma_f32_16x16x32_bf16(al[rt][0], bh0, acc, 0, 0, 0);
                acc = __builtin_amdgcn_mfma_f32_16x16x32_bf16(ah[rt][0], bl0, acc, 0, 0, 0);
                acc = __builtin_amdgcn_mfma_f32_16x16x32_bf16(ah[rt][1], bh1, acc, 0, 0, 0);
                acc = __builtin_amdgcn_mfma_f32_16x16x32_bf16(al[rt][1], bh1, acc, 0, 0, 0);
                acc = __builtin_amdgcn_mfma_f32_16x16x32_bf16(ah[rt][1], bl1, acc, 0, 0, 0);
#pragma unroll
                for (int r = 0; r < 4; ++r) {
                    float s = fmaf(-2.0f, acc[r], wsqc);   // xsq dropped: row-constant
                    bool lt = s < m1[rt][r];
                    m2[rt][r] = fminf(m2[rt][r], fmaxf(s, m1[rt][r]));  // uses old m1
                    i1[rt][r] = lt ? kc : i1[rt][r];
                    m1[rt][r] = fminf(m1[rt][r], s);
                }
            }
        }
        __syncthreads();   // tile kt+1 landed; everyone done with buf[cur]
    }

    // ---- cross-lane top-2 merge within each 16-lane (ln15) group
#pragma unroll
    for (int rt = 0; rt < 4; ++rt)
#pragma unroll
        for (int r = 0; r < 4; ++r) {
            float a1 = m1[rt][r]; int ai = i1[rt][r]; float a2 = m2[rt][r];
#pragma unroll
            for (int mask = 1; mask < 16; mask <<= 1) {
                float b1 = __shfl_xor(a1, mask, 64);
                int   bi = __shfl_xor(ai, mask, 64);
                float b2 = __shfl_xor(a2, mask, 64);
                float n2 = fminf(fminf(a2, b2), fmaxf(a1, b1));
                if (b1 < a1 || (b1 == a1 && bi < ai)) { a1 = b1; ai = bi; }
                a2 = n2;
            }
            if (ln15 == 0) {
                int row = wid * 64 + rt * 16 + quad * 4 + r;
                idxRow[row] = ai;
                gapRow[row] = a2 - a1;
            }
        }
    __syncthreads();

    // ---- outputs
    iout[rowBase + t] = (float)idxRow[t];
    if (gapRow[t] < EPS) {
        int pos = atomicAdd(counter, 1);
        if (pos < cap) list[pos] = (int)(rowBase + t);
    }
#pragma unroll
    for (int it = 0; it < 16; ++it) {
        int cid = it * 256 + t;            // 4096 float4 chunks
        int row = cid >> 4, seg = cid & 15;
        int idx = idxRow[row];
        reinterpret_cast<f32x4*>(qout + (rowBase + row) * VQ_D)[seg] =
            reinterpret_cast<const f32x4*>(w + (size_t)idx * VQ_D)[seg];
    }
}

// ---------------- kernel 2: exact fp32 re-solve of flagged rows (block per row)
__global__ __launch_bounds__(256) void vq_fix_kernel(
    const float* __restrict__ x, const float* __restrict__ w,
    const float* __restrict__ wsq_g,
    const int* __restrict__ counter, const int* __restrict__ list, int cap,
    float* __restrict__ qout, float* __restrict__ iout, int N) {

    __shared__ __align__(16) float xs[VQ_D];
    __shared__ float bmS[4];
    __shared__ int   bkS[4];
    __shared__ int   bestK;

    const int t = threadIdx.x, lane = t & 63, wid = t >> 6;
    int cnt = *counter;
    bool ovf = cnt > cap;
    int nwork = ovf ? N : cnt;

    for (int i = blockIdx.x; i < nwork; i += gridDim.x) {
        int row = ovf ? i : list[i];
        if (t < 16)
            reinterpret_cast<f32x4*>(xs)[t] =
                reinterpret_cast<const f32x4*>(x + (size_t)row * VQ_D)[t];
        __syncthreads();

        f32x4 xv[16];
#pragma unroll
        for (int j = 0; j < 16; ++j) xv[j] = reinterpret_cast<const f32x4*>(xs)[j];
        float sx = 0.f, sy = 0.f, sz = 0.f, sw = 0.f;
#pragma unroll
        for (int j = 0; j < 16; ++j) {
            sx = fmaf(xv[j][0], xv[j][0], sx); sy = fmaf(xv[j][1], xv[j][1], sy);
            sz = fmaf(xv[j][2], xv[j][2], sz); sw = fmaf(xv[j][3], xv[j][3], sw);
        }
        float xsq = (sx + sy) + (sz + sw);

        float bm = 3.402823466e38f; int bk = 0x7fffffff;
#pragma unroll
        for (int p = 0; p < 4; ++p) {
            int k = t * 4 + p;                      // ascending per thread
            const f32x4* wr = reinterpret_cast<const f32x4*>(w + (size_t)k * VQ_D);
            float ax = 0.f, ay = 0.f, az = 0.f, aw = 0.f;
#pragma unroll
            for (int j = 0; j < 16; ++j) {
                f32x4 v = wr[j];
                ax = fmaf(xv[j][0], v[0], ax); ay = fmaf(xv[j][1], v[1], ay);
                az = fmaf(xv[j][2], v[2], az); aw = fmaf(xv[j][3], v[3], aw);
            }
            float dot = (ax + ay) + (az + aw);
            float s = (xsq - 2.0f * dot) + wsq_g[k];  // bit-identical to round-2 path
            if (s < bm) { bm = s; bk = k; }
        }
        // wave reduce (min value, min index on ties)
#pragma unroll
        for (int mask = 1; mask < 64; mask <<= 1) {
            float om = __shfl_xor(bm, mask, 64);
            int   ok = __shfl_xor(bk, mask, 64);
            if (om < bm || (om == bm && ok < bk)) { bm = om; bk = ok; }
        }
        if (lane == 0) { bmS[wid] = bm; bkS[wid] = bk; }
        __syncthreads();
        if (t == 0) {
            float fm = bmS[0]; int fk = bkS[0];
#pragma unroll
            for (int wv = 1; wv < 4; ++wv) {
                if (bmS[wv] < fm || (bmS[wv] == fm && bkS[wv] < fk)) { fm = bmS[wv]; fk = bkS[wv]; }
            }
            bestK = fk;
            iout[row] = (float)fk;
        }
        __syncthreads();
        int bkf = bestK;
        if (t < VQ_D) qout[(size_t)row * VQ_D + t] = w[(size_t)bkf * VQ_D + t];
        __syncthreads();   // protect xs/bmS/bestK before next iteration
    }
}

extern "C" void kernel_launch(void* const* d_in, const int* in_sizes, int n_in,
                              void* d_out, int out_size, void* d_ws, size_t ws_size,
                              hipStream_t stream) {
    const float* x = (const float*)d_in[0];
    const float* w = (const float*)d_in[1];
    const int N = in_sizes[0] / VQ_D;      // 262144

    float* qout = (float*)d_out;
    float* iout = qout + (size_t)N * VQ_D;

    // workspace layout
    char* ws = (char*)d_ws;
    short* wS    = (short*)(ws);                       // 16 tiles * 8192 shorts = 256 KiB
    float* wsq_g = (float*)(ws + 262144);              // 4 KiB
    int*   counter = (int*)(ws + 266240);              // 4 B
    int*   list    = (int*)(ws + 266244);
    long long capLL = ((long long)ws_size - 266244) / 4;
    int cap = capLL < 0 ? 0 : (capLL > N ? N : (int)capLL);

    vq_prep_kernel<<<VQ_K / 256, 256, 0, stream>>>(w, wS, wsq_g, counter);
    vq_main_kernel<<<N / ROWS_PER_BLOCK, 256, 0, stream>>>(
        x, wS, wsq_g, w, qout, iout, counter, list, cap);
    vq_fix_kernel<<<512, 256, 0, stream>>>(x, w, wsq_g, counter, list, cap, qout, iout, N);
}

// Round 5
// 246.232 us; speedup vs baseline: 2.9292x; 1.3401x over previous
//
#include <hip/hip_runtime.h>
#include <hip/hip_bf16.h>

#define VQ_D   64
#define VQ_K   1024
#define ROWS_PER_BLOCK 256           // 4 waves x 64 rows
#define EPS    0.015f

typedef __attribute__((ext_vector_type(8))) short short8_t;
typedef __attribute__((ext_vector_type(4))) float f32x4;

static __device__ __forceinline__ short f2bf_s(float f) {
    __hip_bfloat16 b = __float2bfloat16(f);
    short s; __builtin_memcpy(&s, &b, 2); return s;
}
static __device__ __forceinline__ float bf2f(short s) {
    __hip_bfloat16 b; __builtin_memcpy(&b, &s, 2); return __bfloat162float(b);
}

// ---------------- kernel 0: swizzle w into per-lane MFMA fragment order + wsq
// wS layout: chunk T = 16 codes (T = c>>4, 64 chunks) = 2048 shorts:
//   sub 0: hi K-half 0, sub 1: hi K-half 1, sub 2: lo K-half 0, sub 3: lo K-half 1
//   within sub: slot (q*16 + l) * 8 shorts  (q = k-quad, l = code mod 16)
// A lane (quad q, ln15 l) reads its whole fragment as one 16B load at lane*16B.
__global__ __launch_bounds__(256) void vq_prep_kernel(
    const float* __restrict__ w, short* __restrict__ wS,
    float* __restrict__ wsq_g, float* __restrict__ wsqm_g,
    int* __restrict__ counter) {
    const int c = blockIdx.x * 256 + threadIdx.x;   // code id; grid = K/256
    if (c == 0) *counter = 0;
    if (c >= VQ_K) return;
    const int T = c >> 4, l = c & 15;
    short* tbase = wS + (size_t)T * 2048;
    float sx = 0.f, sy = 0.f, sz = 0.f, sw = 0.f;
#pragma unroll
    for (int b = 0; b < 2; ++b)
#pragma unroll
        for (int q = 0; q < 4; ++q) {
            const float* src = w + (size_t)c * VQ_D + b * 32 + q * 8;
            f32x4 v0 = *reinterpret_cast<const f32x4*>(src);
            f32x4 v1 = *reinterpret_cast<const f32x4*>(src + 4);
            float vv[8] = {v0[0], v0[1], v0[2], v0[3], v1[0], v1[1], v1[2], v1[3]};
            short8_t hs, ls;
#pragma unroll
            for (int j = 0; j < 8; ++j) {
                short h = f2bf_s(vv[j]);
                hs[j] = h;
                ls[j] = f2bf_s(vv[j] - bf2f(h));
            }
            *reinterpret_cast<short8_t*>(tbase + b * 512 + (q * 16 + l) * 8) = hs;
            *reinterpret_cast<short8_t*>(tbase + 1024 + b * 512 + (q * 16 + l) * 8) = ls;
            // wsq in EXACT round-2 partial order (f32x4 ascending, 4 chains)
            sx = fmaf(v0[0], v0[0], sx); sy = fmaf(v0[1], v0[1], sy);
            sz = fmaf(v0[2], v0[2], sz); sw = fmaf(v0[3], v0[3], sw);
            sx = fmaf(v1[0], v1[0], sx); sy = fmaf(v1[1], v1[1], sy);
            sz = fmaf(v1[2], v1[2], sz); sw = fmaf(v1[3], v1[3], sw);
        }
    float s = (sx + sy) + (sz + sw);
    wsq_g[c]  = s;            // exact, for fix kernel
    wsqm_g[c] = -0.5f * s;    // MFMA C-bias: argmax(dot - wsq/2) == argmin(wsq - 2dot)
}

// ---------------- kernel 1: barrier-free MFMA scores, top-2, outputs
__global__ __launch_bounds__(256, 2) void vq_main_kernel(
    const float* __restrict__ x, const short* __restrict__ wS,
    const float* __restrict__ wsqm_g, const float* __restrict__ w,
    float* __restrict__ qout, float* __restrict__ iout,
    int* __restrict__ counter, int* __restrict__ list, int cap) {

    __shared__ float wsqm[VQ_K];          // 4 KB
    __shared__ int   idxL[ROWS_PER_BLOCK];
    __shared__ float gapL[ROWS_PER_BLOCK];

    const int t    = threadIdx.x;
    const int wid  = t >> 6;
    const int lane = t & 63;
    const int quad = lane >> 4;
    const int ln15 = lane & 15;
    const long long rowBase = (long long)blockIdx.x * ROWS_PER_BLOCK;

    // ---- stage wsqm (block-shared, one barrier total)
#pragma unroll
    for (int i = 0; i < 4; ++i) wsqm[i * 256 + t] = wsqm_g[i * 256 + t];

    // ---- A fragments straight from global x (hi/lo bf16 split)
    short8_t ah[4][2], al[4][2];
#pragma unroll
    for (int rt = 0; rt < 4; ++rt)
#pragma unroll
        for (int ks = 0; ks < 2; ++ks) {
            const float* xp = x + (rowBase + wid * 64 + rt * 16 + ln15) * VQ_D + ks * 32 + quad * 8;
            f32x4 v0 = *reinterpret_cast<const f32x4*>(xp);
            f32x4 v1 = *reinterpret_cast<const f32x4*>(xp + 4);
            float vv[8] = {v0[0], v0[1], v0[2], v0[3], v1[0], v1[1], v1[2], v1[3]};
#pragma unroll
            for (int j = 0; j < 8; ++j) {
                short h = f2bf_s(vv[j]);
                ah[rt][ks][j] = h;
                al[rt][ks][j] = f2bf_s(vv[j] - bf2f(h));
            }
        }

    float m1[4][4], m2[4][4]; int i1[4][4];
#pragma unroll
    for (int rt = 0; rt < 4; ++rt)
#pragma unroll
        for (int r = 0; r < 4; ++r) {
            m1[rt][r] = -3.402823466e38f; m2[rt][r] = -3.402823466e38f; i1[rt][r] = 0;
        }

    __syncthreads();   // wsqm ready (the ONLY hot-path barrier)

    const int laneoff = lane * 8;     // shorts
    for (int kt = 0; kt < VQ_K / 64; ++kt) {
#pragma unroll
        for (int ct = 0; ct < 4; ++ct) {
            const short* cb = wS + (size_t)(kt * 4 + ct) * 2048 + laneoff;
            short8_t bh0 = *reinterpret_cast<const short8_t*>(cb);
            short8_t bh1 = *reinterpret_cast<const short8_t*>(cb + 512);
            short8_t bl0 = *reinterpret_cast<const short8_t*>(cb + 1024);
            short8_t bl1 = *reinterpret_cast<const short8_t*>(cb + 1536);
            const int   kc = kt * 64 + ct * 16 + ln15;
            const float wm = wsqm[kc];     // 16 banks, 4-way broadcast: conflict-free
#pragma unroll
            for (int rt = 0; rt < 4; ++rt) {
                f32x4 acc = {wm, wm, wm, wm};   // C-bias: acc = dot - wsq/2
                acc = __builtin_amdgcn_mfma_f32_16x16x32_bf16(ah[rt][0], bh0, acc, 0, 0, 0);
                acc = __builtin_amdgcn_mfma_f32_16x16x32_bf16(al[rt][0], bh0, acc, 0, 0, 0);
                acc = __builtin_amdgcn_mfma_f32_16x16x32_bf16(ah[rt][0], bl0, acc, 0, 0, 0);
                acc = __builtin_amdgcn_mfma_f32_16x16x32_bf16(ah[rt][1], bh1, acc, 0, 0, 0);
                acc = __builtin_amdgcn_mfma_f32_16x16x32_bf16(al[rt][1], bh1, acc, 0, 0, 0);
                acc = __builtin_amdgcn_mfma_f32_16x16x32_bf16(ah[rt][1], bl1, acc, 0, 0, 0);
#pragma unroll
                for (int r = 0; r < 4; ++r) {
                    float s = acc[r];                                  // maximize
                    bool gt = s > m1[rt][r];
                    m2[rt][r] = fmaxf(m2[rt][r], fminf(s, m1[rt][r]));
                    i1[rt][r] = gt ? kc : i1[rt][r];
                    m1[rt][r] = fmaxf(m1[rt][r], s);
                }
            }
        }
    }

    // ---- cross-lane top-2 merge within each 16-lane group (no tie logic:
    //      any near-tie has gap < EPS -> flagged -> exact fix resolves it)
#pragma unroll
    for (int rt = 0; rt < 4; ++rt)
#pragma unroll
        for (int r = 0; r < 4; ++r) {
            float a1 = m1[rt][r]; int ai = i1[rt][r]; float a2 = m2[rt][r];
#pragma unroll
            for (int mask = 1; mask < 16; mask <<= 1) {
                float b1 = __shfl_xor(a1, mask, 64);
                int   bi = __shfl_xor(ai, mask, 64);
                float b2 = __shfl_xor(a2, mask, 64);
                float n2 = fmaxf(fmaxf(a2, b2), fminf(a1, b1));
                if (b1 > a1) { a1 = b1; ai = bi; }
                a2 = n2;
            }
            if (ln15 == 0) {
                int row = wid * 64 + rt * 16 + quad * 4 + r;
                idxL[row] = ai;
                gapL[row] = 2.0f * (a1 - a2);    // score-space gap
            }
        }
    __syncthreads();

    // ---- outputs
    iout[rowBase + t] = (float)idxL[t];
    if (gapL[t] < EPS) {
        int pos = atomicAdd(counter, 1);
        if (pos < cap) list[pos] = (int)(rowBase + t);
    }
#pragma unroll
    for (int it = 0; it < 16; ++it) {
        int cid = it * 256 + t;            // 4096 float4 chunks
        int row = cid >> 4, seg = cid & 15;
        int idx = idxL[row];
        reinterpret_cast<f32x4*>(qout + (rowBase + row) * VQ_D)[seg] =
            reinterpret_cast<const f32x4*>(w + (size_t)idx * VQ_D)[seg];
    }
}

// ---------------- kernel 2: exact fp32 re-solve, 4 rows per chunk (codes-outer)
__global__ __launch_bounds__(256) void vq_fix_kernel(
    const float* __restrict__ x, const float* __restrict__ w,
    const float* __restrict__ wsq_g,
    const int* __restrict__ counter, const int* __restrict__ list, int cap,
    float* __restrict__ qout, float* __restrict__ iout, int N) {

    __shared__ __align__(16) float xs[4][VQ_D];
    __shared__ float xsqS[4];
    __shared__ float rv[256];
    __shared__ int   ri[256];
    __shared__ int   rowsS[4];

    const int t = threadIdx.x;
    int cnt = *counter;
    bool ovf = cnt > cap;
    int nwork = ovf ? N : cnt;

    for (int base = blockIdx.x * 4; base < nwork; base += gridDim.x * 4) {
        if (t < 4) {
            int gi = base + t;
            rowsS[t] = (gi < nwork) ? (ovf ? gi : list[gi]) : -1;
        }
        __syncthreads();
        if (t < 64) {
            int j = t >> 4, seg = t & 15;
            int row = rowsS[j];
            if (row >= 0)
                reinterpret_cast<f32x4*>(xs[j])[seg] =
                    reinterpret_cast<const f32x4*>(x + (size_t)row * VQ_D)[seg];
        }
        __syncthreads();
        if (t < 4 && rowsS[t] >= 0) {
            float sx = 0.f, sy = 0.f, sz = 0.f, sw = 0.f;
#pragma unroll
            for (int j16 = 0; j16 < 16; ++j16) {
                f32x4 v = reinterpret_cast<const f32x4*>(xs[t])[j16];
                sx = fmaf(v[0], v[0], sx); sy = fmaf(v[1], v[1], sy);
                sz = fmaf(v[2], v[2], sz); sw = fmaf(v[3], v[3], sw);
            }
            xsqS[t] = (sx + sy) + (sz + sw);
        }
        __syncthreads();

        float bm[4]; int bk[4];
#pragma unroll
        for (int j = 0; j < 4; ++j) { bm[j] = 3.402823466e38f; bk[j] = 0x7fffffff; }

        for (int p = 0; p < 4; ++p) {
            int k = p * 256 + t;                   // ascending per thread
            f32x4 wv[16];
#pragma unroll
            for (int s16 = 0; s16 < 16; ++s16)
                wv[s16] = reinterpret_cast<const f32x4*>(w + (size_t)k * VQ_D)[s16];
            float wsqk = wsq_g[k];
#pragma unroll
            for (int j = 0; j < 4; ++j) {
                float ax = 0.f, ay = 0.f, az = 0.f, aw = 0.f;
#pragma unroll
                for (int s16 = 0; s16 < 16; ++s16) {
                    f32x4 xv = reinterpret_cast<const f32x4*>(xs[j])[s16];  // broadcast
                    ax = fmaf(xv[0], wv[s16][0], ax); ay = fmaf(xv[1], wv[s16][1], ay);
                    az = fmaf(xv[2], wv[s16][2], az); aw = fmaf(xv[3], wv[s16][3], aw);
                }
                float dot = (ax + ay) + (az + aw);
                float s = (xsqS[j] - 2.0f * dot) + wsqk;   // bit-identical round-2 chain
                if (s < bm[j]) { bm[j] = s; bk[j] = k; }
            }
        }

        // per-row block-wide reduce (min value, smallest k on ties)
#pragma unroll
        for (int j = 0; j < 4; ++j) {
            rv[t] = bm[j]; ri[t] = bk[j];
            __syncthreads();
            for (int off = 128; off > 0; off >>= 1) {
                if (t < off) {
                    float ov = rv[t + off]; int oi = ri[t + off];
                    if (ov < rv[t] || (ov == rv[t] && oi < ri[t])) { rv[t] = ov; ri[t] = oi; }
                }
                __syncthreads();
            }
            int row = rowsS[j];
            if (row >= 0) {
                int bestk = ri[0];
                if (t == 0) iout[row] = (float)bestk;
                if (t < VQ_D) qout[(size_t)row * VQ_D + t] = w[(size_t)bestk * VQ_D + t];
            }
            __syncthreads();   // rv/ri reuse
        }
    }
}

extern "C" void kernel_launch(void* const* d_in, const int* in_sizes, int n_in,
                              void* d_out, int out_size, void* d_ws, size_t ws_size,
                              hipStream_t stream) {
    const float* x = (const float*)d_in[0];
    const float* w = (const float*)d_in[1];
    const int N = in_sizes[0] / VQ_D;      // 262144

    float* qout = (float*)d_out;
    float* iout = qout + (size_t)N * VQ_D;

    // workspace layout
    char* ws = (char*)d_ws;
    short* wS      = (short*)(ws);                   // 256 KiB swizzled hi/lo codebook
    float* wsq_g   = (float*)(ws + 262144);          // 4 KiB exact ||w||^2
    float* wsqm_g  = (float*)(ws + 266240);          // 4 KiB  -||w||^2/2 (MFMA bias)
    int*   counter = (int*)(ws + 270336);            // 4 B
    int*   list    = (int*)(ws + 270340);
    long long capLL = ((long long)ws_size - 270340) / 4;
    int cap = capLL < 0 ? 0 : (capLL > N ? N : (int)capLL);

    vq_prep_kernel<<<VQ_K / 256, 256, 0, stream>>>(w, wS, wsq_g, wsqm_g, counter);
    vq_main_kernel<<<N / ROWS_PER_BLOCK, 256, 0, stream>>>(
        x, wS, wsqm_g, w, qout, iout, counter, list, cap);
    vq_fix_kernel<<<512, 256, 0, stream>>>(x, w, wsq_g, counter, list, cap, qout, iout, N);
}